// Round 2
// baseline (660.215 us; speedup 1.0000x reference)
//
#include <hip/hip_runtime.h>

typedef __bf16 bf16;
typedef __bf16 bf16x8 __attribute__((ext_vector_type(8)));
typedef float f32x4 __attribute__((ext_vector_type(4)));

#define XT_BYTES  110166016L   // 64*82*82*128*2  bf16, zero-padded halo
#define W2_BYTES  18874368L    // 64*9*128*128*2  bf16, [b][kpos][och][ic]
#define AVG_BYTES 819200L      // 64*128*5*5 fp32
#define WS_NEEDED (XT_BYTES + W2_BYTES + AVG_BYTES)

__device__ __forceinline__ void gload_lds16(const bf16* g, bf16* l) {
    __builtin_amdgcn_global_load_lds(
        (__attribute__((address_space(1))) void*)g,
        (__attribute__((address_space(3))) void*)l, 16, 0, 0);
}

// ---------------- pool: one wave per 16x16 tile -> avg[b][c][i][j] ----------------
__global__ void pool_kernel(const float* __restrict__ x, float* __restrict__ avg) {
    int wave = (blockIdx.x * blockDim.x + threadIdx.x) >> 6;
    int lane = threadIdx.x & 63;
    int j = wave % 5; int t = wave / 5;
    int i = t % 5; t /= 5;
    int c = t & 127; int b = t >> 7;
    const float* src = x + (((long)(b * 128 + c) * 80) + i * 16) * 80 + j * 16;
    int ry = lane >> 2;
    int rx = (lane & 3) * 4;
    float4 v = *reinterpret_cast<const float4*>(src + ry * 80 + rx);
    float s = v.x + v.y + v.z + v.w;
    #pragma unroll
    for (int off = 32; off > 0; off >>= 1) s += __shfl_down(s, off, 64);
    if (lane == 0) avg[wave] = s * (1.0f / 256.0f);
}

// ------------- transpose: x[b][c][y][x] f32 -> xT[b][Y][X][c] bf16 (padded), halo zeroed -------------
#define TLDS 130
__global__ __launch_bounds__(256)
void transpose_kernel(const float* __restrict__ x, bf16* __restrict__ xT) {
    __shared__ bf16 tile[64 * TLDS];
    int b = blockIdx.y, pxb = blockIdx.x;
    int t = threadIdx.x;
    bf16* xTb = xT + (long)b * 82 * 82 * 128;
    if (pxb == 100) {
        // halo: 324 border pixels * 128 c, zeroed as 16B chunks
        uint4 z = {0u, 0u, 0u, 0u};
        for (int i = t; i < 5184; i += 256) {
            int px = i >> 4, ch = i & 15;
            int Y, X;
            if (px < 82)       { Y = 0;            X = px;       }
            else if (px < 164) { Y = 81;           X = px - 82;  }
            else if (px < 244) { Y = px - 164 + 1; X = 0;        }
            else               { Y = px - 244 + 1; X = 81;       }
            *reinterpret_cast<uint4*>(&xTb[((long)Y * 82 + X) * 128 + ch * 8]) = z;
        }
        return;
    }
    int px0 = pxb * 64;
    const float* xb = x + (long)b * 128 * 6400 + px0;
    #pragma unroll
    for (int it = 0; it < 8; ++it) {
        int idx = it * 256 + t;
        int c = idx >> 4, q = idx & 15;
        float4 v = *reinterpret_cast<const float4*>(xb + (long)c * 6400 + q * 4);
        tile[(q * 4 + 0) * TLDS + c] = (bf16)v.x;
        tile[(q * 4 + 1) * TLDS + c] = (bf16)v.y;
        tile[(q * 4 + 2) * TLDS + c] = (bf16)v.z;
        tile[(q * 4 + 3) * TLDS + c] = (bf16)v.w;
    }
    __syncthreads();
    #pragma unroll
    for (int it = 0; it < 4; ++it) {
        int idx = it * 256 + t;
        int px = idx >> 4, co = idx & 15;
        const unsigned* s = reinterpret_cast<const unsigned*>(&tile[px * TLDS + co * 8]);
        uint4 v; v.x = s[0]; v.y = s[1]; v.z = s[2]; v.w = s[3];
        int pg = px0 + px;
        int Y = pg / 80 + 1, X = pg % 80 + 1;
        *reinterpret_cast<uint4*>(&xTb[((long)Y * 82 + X) * 128 + co * 8]) = v;
    }
}

// ------------- attention: avg -> att -> sigmoid -> dyn_w, W2[b][p][och][ic] bf16 -------------
__global__ void att_kernel(const float* __restrict__ avg, const float* __restrict__ weight,
                           const float* __restrict__ w_att, const float* __restrict__ b_att,
                           bf16* __restrict__ W2) {
    __shared__ float sa[25];
    int b = blockIdx.x >> 7, och = blockIdx.x & 127;
    int ic = threadIdx.x;
    if (ic < 25) sa[ic] = avg[(long)blockIdx.x * 25 + ic];
    __syncthreads();
    int o = och * 128 + ic;
    float wa[9];
    #pragma unroll
    for (int j = 0; j < 9; ++j) wa[j] = w_att[(long)o * 9 + j];
    float bias = b_att[o];
    const float* wst = weight + (long)o * 9;
    #pragma unroll
    for (int kh = 0; kh < 3; ++kh) {
        #pragma unroll
        for (int kw = 0; kw < 3; ++kw) {
            float z = bias;
            #pragma unroll
            for (int di = 0; di < 3; ++di)
                #pragma unroll
                for (int dj = 0; dj < 3; ++dj)
                    z += sa[(kh + di) * 5 + (kw + dj)] * wa[di * 3 + dj];
            float s = 1.0f / (1.0f + __expf(-z));
            float dw = wst[kh * 3 + kw] * s;
            int p = kh * 3 + kw;
            W2[(((long)b * 9 + p) * 128 + och) * 128 + ic] = (bf16)dw;
        }
    }
}

// ------------- main conv: implicit GEMM, A(W) global->regs, B(X) LDS (staged once), 1 barrier -------------
// block: 128 och x 128 pix, 4 waves, wave = 64 och x 64 pix (4x4 subtiles of 16x16x32)
__global__ __launch_bounds__(256, 3)
void conv_gemm(const bf16* __restrict__ xT, const bf16* __restrict__ W2,
               float* __restrict__ out) {
    __shared__ bf16 Xs[180 * 128];   // [pf=r*18+cx][ic], octet slot = icb ^ (pf&7)
    int b = blockIdx.z;
    int px0 = blockIdx.x * 16;       // 0..64
    int py0 = blockIdx.y * 8;        // 0..72
    int t = threadIdx.x;
    int wave = t >> 6, lane = t & 63;
    int q = lane >> 4, li = lane & 15;

    // ---- stage X tile via global_load_lds: 180 rows x 256B = 45 chunks of 1KB
    {
        const bf16* src = xT + (((long)b * 82 + py0) * 82 + px0) * 128;
        for (int ch = wave; ch < 45; ch += 4) {
            int pf = ch * 4 + (lane >> 4);
            int slot = lane & 15;
            int icb = slot ^ (pf & 7);
            int r = pf / 18, cx = pf - r * 18;
            gload_lds16(src + ((long)r * 82 + cx) * 128 + icb * 8,
                        &Xs[ch * 512 + lane * 8]);
        }
    }

    f32x4 acc[4][4];
    #pragma unroll
    for (int i = 0; i < 4; ++i)
        #pragma unroll
        for (int j = 0; j < 4; ++j) acc[i][j] = (f32x4){0.f, 0.f, 0.f, 0.f};

    int ow = (wave >> 1) * 64;   // och offset of this wave
    int nw = (wave & 1) * 64;    // pixel offset of this wave
    int oyb = nw >> 4;           // 0 or 4

    __syncthreads();             // drains global_load_lds (vmcnt) + all waves staged

    const bf16* wb = W2 + (long)b * 9 * 16384;
    for (int p = 0; p < 9; ++p) {
        int kh = p / 3, kw = p - kh * 3;
        const bf16* wp = wb + p * 16384;
        #pragma unroll
        for (int k2 = 0; k2 < 4; ++k2) {
            bf16x8 af[4], bfr[4];
            #pragma unroll
            for (int mi = 0; mi < 4; ++mi)
                af[mi] = *reinterpret_cast<const bf16x8*>(
                    wp + (ow + mi * 16 + li) * 128 + (k2 * 4 + q) * 8);
            #pragma unroll
            for (int ni = 0; ni < 4; ++ni) {
                int pf = (oyb + ni + kh) * 18 + li + kw;
                int slot = (k2 * 4 + q) ^ (pf & 7);
                bfr[ni] = *reinterpret_cast<const bf16x8*>(&Xs[pf * 128 + slot * 8]);
            }
            #pragma unroll
            for (int mi = 0; mi < 4; ++mi)
                #pragma unroll
                for (int ni = 0; ni < 4; ++ni)
                    acc[mi][ni] = __builtin_amdgcn_mfma_f32_16x16x32_bf16(af[mi], bfr[ni], acc[mi][ni], 0, 0, 0);
        }
    }

    // epilogue: D[row=q*4+reg][col=li]; row->och, col->pixel
    #pragma unroll
    for (int mi = 0; mi < 4; ++mi) {
        #pragma unroll
        for (int ni = 0; ni < 4; ++ni) {
            int n = nw + ni * 16 + li;
            int oy = py0 + (n >> 4), ox = px0 + (n & 15);
            #pragma unroll
            for (int r = 0; r < 4; ++r) {
                int och = ow + mi * 16 + q * 4 + r;
                out[((long)(b * 128 + och) * 80 + oy) * 80 + ox] = acc[mi][ni][r];
            }
        }
    }
}

extern "C" void kernel_launch(void* const* d_in, const int* in_sizes, int n_in,
                              void* d_out, int out_size, void* d_ws, size_t ws_size,
                              hipStream_t stream) {
    const float* x      = (const float*)d_in[0];
    const float* weight = (const float*)d_in[1];
    const float* w_att  = (const float*)d_in[2];
    const float* b_att  = (const float*)d_in[3];
    float* out = (float*)d_out;

    if (ws_size < (size_t)WS_NEEDED) return;

    char* ws = (char*)d_ws;
    bf16* xT  = (bf16*)ws;
    bf16* W2  = (bf16*)(ws + XT_BYTES);
    float* avg = (float*)(ws + XT_BYTES + W2_BYTES);

    pool_kernel<<<51200, 256, 0, stream>>>(x, avg);
    transpose_kernel<<<dim3(101, 64), 256, 0, stream>>>(x, xT);
    att_kernel<<<8192, 128, 0, stream>>>(avg, weight, w_att, b_att, W2);
    conv_gemm<<<dim3(5, 10, 64), 256, 0, stream>>>(xT, W2, out);
}